// Round 14
// baseline (131.804 us; speedup 1.0000x reference)
//
#include <hip/hip_runtime.h>
#include <hip/hip_fp16.h>
#include <math.h>

#define NSEG 66                 // segments 0..65; valid bins 1..64
typedef unsigned uv2 __attribute__((ext_vector_type(2)));
typedef unsigned h2u;           // half2 bit pattern: lo = re, hi = im

__device__ __forceinline__ int brev6(int l) {
    return ((l&1)<<5)|((l&2)<<3)|((l&4)<<1)|((l&8)>>1)|((l&16)>>3)|((l&32)>>5);
}
__device__ __forceinline__ h2u f2h(float a, float b) {
    __half2 h = __floats2half2_rn(a, b); return *reinterpret_cast<unsigned*>(&h);
}
__device__ __forceinline__ h2u shflu(h2u x, int src) {
    return __float_as_uint(__shfl(__uint_as_float(x), src));
}

// ---------------- packed f16 primitives (VOP3P) ----------------
__device__ __forceinline__ h2u pkh_fma(h2u a, h2u b, h2u c) {
    h2u d; asm("v_pk_fma_f16 %0, %1, %2, %3" : "=v"(d) : "v"(a), "v"(b), "v"(c));
    return d;
}
__device__ __forceinline__ h2u pkh_mul(h2u a, h2u b) {
    h2u d; asm("v_pk_mul_f16 %0, %1, %2" : "=v"(d) : "v"(a), "v"(b));
    return d;
}
__device__ __forceinline__ h2u pkh_add(h2u a, h2u b) {
    h2u d; asm("v_pk_add_f16 %0, %1, %2" : "=v"(d) : "v"(a), "v"(b));
    return d;
}
__device__ __forceinline__ h2u pkh_sub(h2u a, h2u b) {
    h2u d; asm("v_pk_add_f16 %0, %1, %2 neg_lo:[0,1] neg_hi:[0,1]" : "=v"(d) : "v"(a), "v"(b));
    return d;
}
__device__ __forceinline__ h2u pkh_addmi(h2u a, h2u b) {  // a - i*b
    h2u d; asm("v_pk_add_f16 %0, %1, %2 op_sel:[0,1] op_sel_hi:[1,0] neg_hi:[0,1]"
               : "=v"(d) : "v"(a), "v"(b));
    return d;
}
__device__ __forceinline__ h2u pkh_addpi(h2u a, h2u b) {  // a + i*b
    h2u d; asm("v_pk_add_f16 %0, %1, %2 op_sel:[0,1] op_sel_hi:[1,0] neg_lo:[0,1]"
               : "=v"(d) : "v"(a), "v"(b));
    return d;
}
// complex mul: z=(x,y), ta=(c,s), tb=(-s,s) -> (xc - ys, xs + yc)
__device__ __forceinline__ h2u cmulh(h2u z, h2u ta, h2u tb) {
    h2u p, r;
    asm("v_pk_mul_f16 %0, %1, %2 op_sel:[0,0] op_sel_hi:[1,0]" : "=v"(p) : "v"(z), "v"(ta));
    asm("v_pk_fma_f16 %0, %1, %2, %3 op_sel:[1,0,0] op_sel_hi:[0,1,1]"
        : "=v"(r) : "v"(z), "v"(tb), "v"(p));
    return r;
}
__device__ __forceinline__ h2u pkh_mul_sw0(h2u a, h2u b) {
    h2u d; asm("v_pk_mul_f16 %0, %1, %2 op_sel:[1,0] op_sel_hi:[0,1]" : "=v"(d) : "v"(a), "v"(b));
    return d;
}
__device__ __forceinline__ h2u pkh_fma_sw0(h2u a, h2u b, h2u c) {
    h2u d; asm("v_pk_fma_f16 %0, %1, %2, %3 op_sel:[1,0,0] op_sel_hi:[0,1,1]"
               : "=v"(d) : "v"(a), "v"(b), "v"(c));
    return d;
}
// |X|^2 in f32 straight from f16 halves
__device__ __forceinline__ float pow2h(h2u X) {
    float p; const float zf = 0.f;
    asm("v_fma_mix_f32 %0, %2, %2, %1 op_sel:[0,0,0] op_sel_hi:[1,1,0]" : "=v"(p) : "v"(zf), "v"(X));
    asm("v_fma_mix_f32 %0, %1, %1, %0 op_sel:[1,1,0] op_sel_hi:[1,1,0]" : "+v"(p) : "v"(X));
    return p;
}
// byte permute: result byte sel<4 -> lo bytes, 4..7 -> hi bytes
__device__ __forceinline__ unsigned bperm(unsigned hi, unsigned lo, unsigned sel) {
#if __has_builtin(__builtin_amdgcn_perm)
    return __builtin_amdgcn_perm(hi, lo, sel);
#else
    unsigned long long v = ((unsigned long long)hi << 32) | lo;
    unsigned r = 0;
    for (int b = 0; b < 4; ++b) r |= ((unsigned)(v >> (8*((sel>>(8*b))&7))) & 0xFF) << (8*b);
    return r;
#endif
}

#define C_PP 0x38003800u    // half2 ( 0.5,  0.5)
#define C_PM 0xB8003800u    // half2 ( 0.5, -0.5)

struct XTH {
    h2u ta32, tb32, sg32;
    h2u ta16, tb16, sg16;
    h2u ta8,  tb8,  sg8;
    h2u ta4,  tb4,  sg4;
    h2u ta2,  tb2,  sg2;
    h2u sg1;
    h2u wa1, wb1, wa2, wb2, wa3, wb3;   // W256^{brev(L)},^2,^3
    int pl;                             // Hermitian partner lane
};

__device__ __forceinline__ h2u bflyh_pl32(h2u z, h2u sg, h2u ta, h2u tb) {
#if __has_builtin(__builtin_amdgcn_permlane32_swap)
    uv2 r = __builtin_amdgcn_permlane32_swap(z, z, false, false);
    h2u u = pkh_fma(r[1], sg, r[0]);
#else
    h2u c = shflu(z, 0); (void)c;  // unreachable fallback
    h2u u = pkh_fma(z, sg, __float_as_uint(__shfl_xor(__uint_as_float(z), 32)));
#endif
    return cmulh(u, ta, tb);
}
__device__ __forceinline__ h2u bflyh_pl16(h2u z, h2u sg, h2u ta, h2u tb) {
#if __has_builtin(__builtin_amdgcn_permlane16_swap)
    uv2 r = __builtin_amdgcn_permlane16_swap(z, z, false, false);
    h2u u = pkh_fma(r[1], sg, r[0]);
#else
    h2u u = pkh_fma(z, sg, __float_as_uint(__shfl_xor(__uint_as_float(z), 16)));
#endif
    return cmulh(u, ta, tb);
}
template<int CTRL>
__device__ __forceinline__ h2u dppx(h2u x) {
#if __has_builtin(__builtin_amdgcn_update_dpp)
    return (h2u)__builtin_amdgcn_update_dpp((int)x, (int)x, CTRL, 0xF, 0xF, false);
#else
    const int d = (CTRL == 0x128) ? 8 : (CTRL == 0x4E ? 2 : 1);
    return __float_as_uint(__shfl_xor(__uint_as_float(x), d));
#endif
}
template<int CTRL>
__device__ __forceinline__ h2u bflyh_dpp(h2u z, h2u sg, h2u ta, h2u tb) {
    return cmulh(pkh_fma(z, sg, dppx<CTRL>(z)), ta, tb);
}
__device__ __forceinline__ h2u bflyh1(h2u z, h2u sg) {
    return pkh_fma(z, sg, dppx<0xB1>(z));
}
// d=4 on the DS pipe (round-13 lesson: DS overlaps free, VALU is scarce)
__device__ __forceinline__ h2u bflyh_ds4(h2u z, h2u sg, h2u ta, h2u tb) {
    h2u c = (h2u)__builtin_amdgcn_ds_swizzle((int)z, 0x101F);
    return cmulh(pkh_fma(z, sg, c), ta, tb);
}

__device__ __forceinline__ float dpp_scan64(float x, int L) {
#if __has_builtin(__builtin_amdgcn_update_dpp)
    #define UPD(ctrl, rmask) __int_as_float(__builtin_amdgcn_update_dpp( \
        0, __float_as_int(x), ctrl, rmask, 0xF, false))
    x += UPD(0x111, 0xF);   // row_shr:1
    x += UPD(0x112, 0xF);   // row_shr:2
    x += UPD(0x114, 0xF);   // row_shr:4
    x += UPD(0x118, 0xF);   // row_shr:8
    x += UPD(0x142, 0xA);   // row_bcast:15 -> rows 1,3
    x += UPD(0x143, 0xC);   // row_bcast:31 -> rows 2,3
    #undef UPD
    return x;
#else
    #pragma unroll
    for (int off = 1; off < 64; off <<= 1) {
        const float yv = __shfl_up(x, off);
        if (L >= off) x += yv;
    }
    return x;
#endif
}

__device__ __forceinline__ void fft64x4h(h2u z[4], const XTH& T) {
    #pragma unroll
    for (int a = 0; a < 4; ++a) {
        z[a] = bflyh_pl32(z[a], T.sg32, T.ta32, T.tb32);
        z[a] = bflyh_pl16(z[a], T.sg16, T.ta16, T.tb16);
        z[a] = bflyh_dpp<0x128>(z[a], T.sg8, T.ta8, T.tb8);
        z[a] = bflyh_ds4(z[a], T.sg4, T.ta4, T.tb4);
        z[a] = bflyh_dpp<0x4E>(z[a], T.sg2, T.ta2, T.tb2);
        z[a] = bflyh1(z[a], T.sg1);
    }
}
__device__ __forceinline__ void twdft4h(const h2u z[4], const XTH& T, h2u X[4]) {
    h2u g0 = z[0];
    h2u g1 = cmulh(z[1], T.wa1, T.wb1);
    h2u g2 = cmulh(z[2], T.wa2, T.wb2);
    h2u g3 = cmulh(z[3], T.wa3, T.wb3);
    h2u b0 = pkh_add(g0, g2), b1 = pkh_sub(g0, g2);
    h2u b2 = pkh_add(g1, g3), b3 = pkh_sub(g1, g3);
    X[0] = pkh_add(b0, b2);
    X[2] = pkh_sub(b0, b2);
    X[1] = pkh_addmi(b1, b3);
    X[3] = pkh_addpi(b1, b3);
}

// 896 threads (14 waves) per image; 2 blocks/CU. bf8(e5m2-trunc) tile, 128
// rows: row 0 = real-packed columns {0,128}, rows 1..127 = kx. pbuf f32.
__global__ __launch_bounds__(896, 7)
void k_fused(const float* __restrict__ pred, const int4* __restrict__ tbl,
             const int* __restrict__ cnt, const float* __restrict__ mean_cl,
             const float* __restrict__ weighting, float* __restrict__ out,
             float cscale, float invB64) {
    __shared__ __align__(16) unsigned short tile[128 * 256];  // bf8 pairs, 65536 B
    __shared__ __align__(16) float pbuf[14][256];             // 14336 B
    const int tid = threadIdx.x, w = tid >> 6, L = tid & 63;
    const int rL = brev6(L);
    const float PI2 = 6.283185307179586f;

    XTH T;
    {
        auto stw = [&](int d, h2u& ta, h2u& tb, h2u& sg) {
            const float s = (L & d) ? -1.f : 1.f;
            const int e = (L & d) ? (L & (d-1)) * (32/d) : 0;
            float ss, cc; __sincosf(-PI2 * (float)e / 64.f, &ss, &cc);
            ta = f2h(cc, ss); tb = f2h(-ss, ss); sg = f2h(s, s);
        };
        stw(32, T.ta32, T.tb32, T.sg32);
        stw(16, T.ta16, T.tb16, T.sg16);
        stw( 8, T.ta8,  T.tb8,  T.sg8);
        stw( 4, T.ta4,  T.tb4,  T.sg4);
        stw( 2, T.ta2,  T.tb2,  T.sg2);
        const float s1 = (L & 1) ? -1.f : 1.f;
        T.sg1 = f2h(s1, s1);
        float sg, cg;
        __sincosf(-PI2 * (float)rL / 256.f, &sg, &cg);
        const float w2x = cg*cg - sg*sg, w2y = 2.f*cg*sg;
        const float w3x = w2x*cg - w2y*sg, w3y = w2x*sg + w2y*cg;
        T.wa1 = f2h(cg, sg);   T.wb1 = f2h(-sg, sg);
        T.wa2 = f2h(w2x, w2y); T.wb2 = f2h(-w2y, w2y);
        T.wa3 = f2h(w3x, w3y); T.wb3 = f2h(-w3y, w3y);
        T.pl = brev6((64 - rL) & 63);
    }

    // ---------------- row phase: row-pairs p = w + 14i ----------------
    const float* base = pred + (size_t)blockIdx.x * 65536;
    const int sw = rL & 28;
    #pragma unroll 2
    for (int p = w; p < 128; p += 14) {
        const int y = 2 * p;
        const float4 ra = *(const float4*)(base + (size_t)y*256 + 4*L);
        const float4 rb = *(const float4*)(base + (size_t)(y+1)*256 + 4*L);
        h2u z[4] = { f2h(ra.x, rb.x), f2h(ra.y, rb.y), f2h(ra.z, rb.z), f2h(ra.w, rb.w) };
        fft64x4h(z, T);
        h2u X[4]; twdft4h(z, T, X);
        h2u q0 = shflu(X[3], T.pl);
        h2u q1 = shflu(X[2], T.pl);
        if (L == 0) { q0 = X[0]; q1 = X[3]; }
        const int yi = y ^ sw;
        const h2u F = pkh_fma(q0, C_PM, pkh_mul(X[0], C_PP));       // F[kx=rL][y]
        const h2u G = pkh_fma_sw0(q0, C_PP, pkh_mul_sw0(X[0], C_PM)); // F[kx=rL][y+1]
        if (L == 0) {
            // packed row 0: entry[y]=(bf8 F0[y], bf8 F128[y]); F128 pair = X[2]
            const unsigned tmp = bperm(G, F, 0x00000501u);       // [F.b1, G.b1, *, *]
            const unsigned e   = bperm(X[2], tmp, 0x07010500u);  // [F.b1, X2.b1, G.b1, X2.b3]
            *(unsigned*)&tile[y] = e;                            // row 0, yi=y (sw=0)
        } else {
            const unsigned e = bperm(G, F, 0x07050301u);         // [F.b1,F.b3,G.b1,G.b3]
            *(unsigned*)&tile[rL*256 + yi] = e;
        }
        {   // kx = 64 + rL (row 64+rL), same swizzle
            const h2u F2 = pkh_fma(q1, C_PM, pkh_mul(X[1], C_PP));
            const h2u G2 = pkh_fma_sw0(q1, C_PP, pkh_mul_sw0(X[1], C_PM));
            const unsigned e = bperm(G2, F2, 0x07050301u);
            *(unsigned*)&tile[(64+rL)*256 + yi] = e;
        }
    }
    __syncthreads();

    // ---------------- column phase: kx = w + 14t ----------------
    float acc = 0.f;                   // lane accumulates bin (L+1)
    float* pb = pbuf[w];
    auto binpass = [&](float p0, float p1, float p2, float p3, int4 tb) -> float {
        pb[rL] = p0; pb[rL+64] = p1; pb[rL+128] = p2; pb[rL+192] = p3;
        const float4 pv = ((const float4*)pb)[L];
        const float s0 = pv.x, s1 = s0+pv.y, s2 = s1+pv.z, s3 = s2+pv.w;
        const float x = dpp_scan64(s3, L);
        const float ex = x - s3;
        ((float4*)pb)[L] = make_float4(ex+s0, ex+s1, ex+s2, ex+s3);
        float gy = pb[tb.y & 255], gx = pb[tb.x & 255];
        float gw = pb[tb.w & 255], gz = pb[tb.z & 255];
        gy = (tb.y < 0) ? 0.f : gy;  gx = (tb.x < 0) ? 0.f : gx;
        gw = (tb.w < 0) ? 0.f : gw;  gz = (tb.z < 0) ? 0.f : gz;
        return gy - gx + gw - gz;
    };
    #pragma unroll 2
    for (int kx = w; kx <= 127; kx += 14) {
        const int cs = kx & 28;
        const uint2 uu = *(const uint2*)&tile[kx*256 + ((4*L) ^ cs)];
        h2u z[4] = { bperm(0u, uu.x, 0x01040004u), bperm(0u, uu.x, 0x03040204u),
                     bperm(0u, uu.y, 0x01040004u), bperm(0u, uu.y, 0x03040204u) };
        fft64x4h(z, T);
        h2u X[4]; twdft4h(z, T, X);    // X[q] = C[k = brev(L) + 64q]
        if (kx == 0) {                 // wave 0 only: packed real cols {0,128}
            h2u Xp0 = shflu(X[3], T.pl), Xp1 = shflu(X[2], T.pl);
            h2u Xp2 = shflu(X[1], T.pl), Xp3 = shflu(X[0], T.pl);
            if (L == 0) { Xp0 = X[0]; Xp1 = X[3]; Xp2 = X[2]; Xp3 = X[1]; }
            // H0 = (C + conj(Cp))/2  (col 0);  H1 = -i(C - conj(Cp))/2  (col 128)
            const float a0 = pow2h(pkh_fma(Xp0, C_PM, pkh_mul(X[0], C_PP)));
            const float a1 = pow2h(pkh_fma(Xp1, C_PM, pkh_mul(X[1], C_PP)));
            const float a2 = pow2h(pkh_fma(Xp2, C_PM, pkh_mul(X[2], C_PP)));
            const float a3 = pow2h(pkh_fma(Xp3, C_PM, pkh_mul(X[3], C_PP)));
            const float b0 = pow2h(pkh_fma_sw0(Xp0, C_PP, pkh_mul_sw0(X[0], C_PM)));
            const float b1 = pow2h(pkh_fma_sw0(Xp1, C_PP, pkh_mul_sw0(X[1], C_PM)));
            const float b2 = pow2h(pkh_fma_sw0(Xp2, C_PP, pkh_mul_sw0(X[2], C_PM)));
            const float b3 = pow2h(pkh_fma_sw0(Xp3, C_PP, pkh_mul_sw0(X[3], C_PM)));
            const int4 tbA = tbl[0*64 + L];
            const int4 tbB = tbl[128*64 + L];
            acc += binpass(a0, a1, a2, a3, tbA);    // symw = 1
            acc += binpass(b0, b1, b2, b3, tbB);    // symw = 1
        } else {
            const int4 tb = tbl[kx*64 + L];
            const float p0 = pow2h(X[0]), p1 = pow2h(X[1]);
            const float p2 = pow2h(X[2]), p3 = pow2h(X[3]);
            acc = fmaf(2.f, binpass(p0, p1, p2, p3, tb), acc);   // kx 1..127: symw = 2
        }
    }
    __syncthreads();

    // ---------------- reduce 14 waves, per-image loss ----------------
    float* bins = (float*)tile;        // tile dead now
    bins[w*64 + L] = acc;
    __syncthreads();
    if (tid < 64) {
        float tot = 0.f;
        #pragma unroll
        for (int ww = 0; ww < 14; ++ww) tot += bins[ww*64 + tid];
        const int c = cnt[tid + 1];
        const float inv = (c > 0) ? 1.0f / (float)c : 0.0f;
        const float v = tot * cscale * inv;
        const float d = logf(v + 1e-12f) - logf(mean_cl[tid] + 1e-12f);
        float l = weighting[tid] * d * d;
        #pragma unroll
        for (int o = 32; o; o >>= 1) l += __shfl_down(l, o);
        if (tid == 0) atomicAdd(out, l * invB64);
    }
}

// Prep: one block per kx row (0..255). Counts for all rows; boundary table
// for rows 0..128: <=2 contiguous ky-runs as prefix indices, -1 = "zero".
__global__ __launch_bounds__(256) void k_prep(const int* __restrict__ seg,
                                              int4* __restrict__ tbl,
                                              int* __restrict__ cnt) {
    __shared__ int lo1[NSEG], hi1[NSEG], lo2[NSEG], hi2[NSEG], lc[NSEG];
    const int kx = blockIdx.x, ky = threadIdx.x;
    if (ky < NSEG) { lo1[ky] = 300; hi1[ky] = -1; lo2[ky] = 300; hi2[ky] = -1; lc[ky] = 0; }
    __syncthreads();
    const int s = seg[kx * 256 + ky];
    atomicAdd(&lc[s], 1);
    if (kx <= 128) {
        if (ky <= 128) { atomicMin(&lo1[s], ky); atomicMax(&hi1[s], ky); }
        else           { atomicMin(&lo2[s], ky); atomicMax(&hi2[s], ky); }
    }
    __syncthreads();
    if (ky < NSEG && lc[ky] > 0) atomicAdd(&cnt[ky], lc[ky]);
    if (kx <= 128 && ky >= 1 && ky <= 64) {
        int4 t;
        if (hi1[ky] < 0) { t.x = -1; t.y = -1; }
        else             { t.x = lo1[ky] - 1; t.y = hi1[ky]; }   // lo1=0 -> -1
        if (hi2[ky] < 0) { t.z = -1; t.w = -1; }
        else             { t.z = lo2[ky] - 1; t.w = hi2[ky]; }
        tbl[kx * 64 + (ky - 1)] = t;
    }
}

extern "C" void kernel_launch(void* const* d_in, const int* in_sizes, int n_in,
                              void* d_out, int out_size, void* d_ws, size_t ws_size,
                              hipStream_t stream) {
    const float* pred      = (const float*)d_in[0];
    const float* mean_cl   = (const float*)d_in[1];
    const float* weighting = (const float*)d_in[2];
    const int*   seg       = (const int*)d_in[3];
    float* out = (float*)d_out;

    const int B = in_sizes[0] / 65536;

    // ws: [cnt 66 i32, pad to 256B][boundary table 129*64 int4]
    int*  cnt = (int*)d_ws;
    int4* tbl = (int4*)((char*)d_ws + 256);

    const double rad = (5.0 * 60.0 / 256.0) * M_PI / 180.0;
    const float cscale = (float)(rad * rad / (65536.0 * 1e12)); // rad^2/N^2/TSZ^2
    const float invB64 = (float)(1.0 / ((double)B * 64.0));

    hipMemsetAsync(d_out, 0, sizeof(float), stream);
    hipMemsetAsync(cnt, 0, NSEG * sizeof(int), stream);
    k_prep<<<256, 256, 0, stream>>>(seg, tbl, cnt);
    k_fused<<<B, 896, 0, stream>>>(pred, tbl, cnt, mean_cl, weighting,
                                   out, cscale, invB64);
}

// Round 15
// 121.741 us; speedup vs baseline: 1.0827x; 1.0827x over previous
//
#include <hip/hip_runtime.h>
#include <hip/hip_fp16.h>
#include <math.h>

#define NSEG 66                 // segments 0..65; valid bins 1..64
typedef unsigned uv2 __attribute__((ext_vector_type(2)));
typedef unsigned h2u;           // half2 bit pattern: lo = re, hi = im

__device__ __forceinline__ int brev6(int l) {
    return ((l&1)<<5)|((l&2)<<3)|((l&4)<<1)|((l&8)>>1)|((l&16)>>3)|((l&32)>>5);
}
__device__ __forceinline__ h2u f2h(float a, float b) {
    __half2 h = __floats2half2_rn(a, b); return *reinterpret_cast<unsigned*>(&h);
}

// ---------------- packed f16 primitives (VOP3P, one VGPR per complex) ----------------
__device__ __forceinline__ h2u pkh_fma(h2u a, h2u b, h2u c) {   // a*b + c (per half)
    h2u d; asm("v_pk_fma_f16 %0, %1, %2, %3" : "=v"(d) : "v"(a), "v"(b), "v"(c));
    return d;
}
__device__ __forceinline__ h2u pkh_mul(h2u a, h2u b) {
    h2u d; asm("v_pk_mul_f16 %0, %1, %2" : "=v"(d) : "v"(a), "v"(b));
    return d;
}
__device__ __forceinline__ h2u pkh_add(h2u a, h2u b) {
    h2u d; asm("v_pk_add_f16 %0, %1, %2" : "=v"(d) : "v"(a), "v"(b));
    return d;
}
__device__ __forceinline__ h2u pkh_sub(h2u a, h2u b) {
    h2u d; asm("v_pk_add_f16 %0, %1, %2 neg_lo:[0,1] neg_hi:[0,1]" : "=v"(d) : "v"(a), "v"(b));
    return d;
}
__device__ __forceinline__ h2u pkh_addmi(h2u a, h2u b) {  // a - i*b = (a.lo+b.hi, a.hi-b.lo)
    h2u d; asm("v_pk_add_f16 %0, %1, %2 op_sel:[0,1] op_sel_hi:[1,0] neg_hi:[0,1]"
               : "=v"(d) : "v"(a), "v"(b));
    return d;
}
__device__ __forceinline__ h2u pkh_addpi(h2u a, h2u b) {  // a + i*b = (a.lo-b.hi, a.hi+b.lo)
    h2u d; asm("v_pk_add_f16 %0, %1, %2 op_sel:[0,1] op_sel_hi:[1,0] neg_lo:[0,1]"
               : "=v"(d) : "v"(a), "v"(b));
    return d;
}
// complex mul: z=(x,y), ta=(c,s), tb=(-s,s) -> (xc - ys, xs + yc)
__device__ __forceinline__ h2u cmulh(h2u z, h2u ta, h2u tb) {
    h2u p, r;
    asm("v_pk_mul_f16 %0, %1, %2 op_sel:[0,0] op_sel_hi:[1,0]" : "=v"(p) : "v"(z), "v"(ta));
    asm("v_pk_fma_f16 %0, %1, %2, %3 op_sel:[1,0,0] op_sel_hi:[0,1,1]"
        : "=v"(r) : "v"(z), "v"(tb), "v"(p));
    return r;
}
// swapped-src0 variants for the Hermitian unpack
__device__ __forceinline__ h2u pkh_mul_sw0(h2u a, h2u b) {  // (a.hi*b.lo, a.lo*b.hi)
    h2u d; asm("v_pk_mul_f16 %0, %1, %2 op_sel:[1,0] op_sel_hi:[0,1]" : "=v"(d) : "v"(a), "v"(b));
    return d;
}
__device__ __forceinline__ h2u pkh_fma_sw0(h2u a, h2u b, h2u c) { // (a.hi*b.lo+c.lo, a.lo*b.hi+c.hi)
    h2u d; asm("v_pk_fma_f16 %0, %1, %2, %3 op_sel:[1,0,0] op_sel_hi:[0,1,1]"
               : "=v"(d) : "v"(a), "v"(b), "v"(c));
    return d;
}

#define C_PP 0x38003800u    // half2 ( 0.5,  0.5)
#define C_PM 0xB8003800u    // half2 ( 0.5, -0.5)

// Per-lane constants (all f16-packed, one VGPR each).
struct XTH {
    h2u ta32, tb32, sg32;
    h2u ta16, tb16, sg16;
    h2u ta8,  tb8,  sg8;
    h2u ta4,  tb4,  sg4;
    h2u ta2,  tb2,  sg2;
    h2u sg1;
    h2u wa1, wb1, wa2, wb2, wa3, wb3;   // W256^{brev(L)},^2,^3
    int pl;                             // Hermitian partner lane
};

// ---- cross-lane exchange + packed butterfly ----
__device__ __forceinline__ h2u bflyh_pl32(h2u z, h2u sg, h2u ta, h2u tb) {
#if __has_builtin(__builtin_amdgcn_permlane32_swap)
    uv2 r = __builtin_amdgcn_permlane32_swap(z, z, false, false);
    h2u u = pkh_fma(r[1], sg, r[0]);
#else
    h2u c = __float_as_uint(__shfl_xor(__uint_as_float(z), 32));
    h2u u = pkh_fma(z, sg, c);
#endif
    return cmulh(u, ta, tb);
}
__device__ __forceinline__ h2u bflyh_pl16(h2u z, h2u sg, h2u ta, h2u tb) {
#if __has_builtin(__builtin_amdgcn_permlane16_swap)
    uv2 r = __builtin_amdgcn_permlane16_swap(z, z, false, false);
    h2u u = pkh_fma(r[1], sg, r[0]);
#else
    h2u c = __float_as_uint(__shfl_xor(__uint_as_float(z), 16));
    h2u u = pkh_fma(z, sg, c);
#endif
    return cmulh(u, ta, tb);
}
template<int CTRL>
__device__ __forceinline__ h2u dppx(h2u x) {
#if __has_builtin(__builtin_amdgcn_update_dpp)
    return (h2u)__builtin_amdgcn_update_dpp((int)x, (int)x, CTRL, 0xF, 0xF, false);
#else
    const int d = (CTRL == 0x128) ? 8 : (CTRL == 0x4E ? 2 : 1);
    return __float_as_uint(__shfl_xor(__uint_as_float(x), d));
#endif
}
template<int CTRL>
__device__ __forceinline__ h2u bflyh_dpp(h2u z, h2u sg, h2u ta, h2u tb) {
    return cmulh(pkh_fma(z, sg, dppx<CTRL>(z)), ta, tb);
}
__device__ __forceinline__ h2u bflyh1(h2u z, h2u sg) {   // d=1, tw==1
    return pkh_fma(z, sg, dppx<0xB1>(z));
}
// d=4 on the DS pipe: ds_swizzle BitMode xor4 = 0x101F. (r13/r14 lesson:
// DS ops overlap free; replacing them with VALU ops regresses.)
__device__ __forceinline__ h2u bflyh_ds4(h2u z, h2u sg, h2u ta, h2u tb) {
    h2u c = (h2u)__builtin_amdgcn_ds_swizzle((int)z, 0x101F);
    return cmulh(pkh_fma(z, sg, c), ta, tb);
}

// 64-lane inclusive prefix sum on the VALU (DPP scan), f32.
__device__ __forceinline__ float dpp_scan64(float x, int L) {
#if __has_builtin(__builtin_amdgcn_update_dpp)
    #define UPD(ctrl, rmask) __int_as_float(__builtin_amdgcn_update_dpp( \
        0, __float_as_int(x), ctrl, rmask, 0xF, false))
    x += UPD(0x111, 0xF);   // row_shr:1
    x += UPD(0x112, 0xF);   // row_shr:2
    x += UPD(0x114, 0xF);   // row_shr:4
    x += UPD(0x118, 0xF);   // row_shr:8
    x += UPD(0x142, 0xA);   // row_bcast:15 -> rows 1,3
    x += UPD(0x143, 0xC);   // row_bcast:31 -> rows 2,3
    #undef UPD
    return x;
#else
    #pragma unroll
    for (int off = 1; off < 64; off <<= 1) {
        const float yv = __shfl_up(x, off);
        if (L >= off) x += yv;
    }
    return x;
#endif
}

// Four independent 64-pt FFTs in f16; result at lane L is G[brev6(L)].
__device__ __forceinline__ void fft64x4h(h2u z[4], const XTH& T) {
    #pragma unroll
    for (int a = 0; a < 4; ++a) {
        z[a] = bflyh_pl32(z[a], T.sg32, T.ta32, T.tb32);
        z[a] = bflyh_pl16(z[a], T.sg16, T.ta16, T.tb16);
        z[a] = bflyh_dpp<0x128>(z[a], T.sg8, T.ta8, T.tb8);
        z[a] = bflyh_ds4(z[a], T.sg4, T.ta4, T.tb4);
        z[a] = bflyh_dpp<0x4E>(z[a], T.sg2, T.ta2, T.tb2);
        z[a] = bflyh1(z[a], T.sg1);
    }
}
// Twiddle by W256^{a*brev(L)} then in-lane DFT4: X[q] = F[brev6(L) + 64q].
__device__ __forceinline__ void twdft4h(const h2u z[4], const XTH& T, h2u X[4]) {
    h2u g0 = z[0];
    h2u g1 = cmulh(z[1], T.wa1, T.wb1);
    h2u g2 = cmulh(z[2], T.wa2, T.wb2);
    h2u g3 = cmulh(z[3], T.wa3, T.wb3);
    h2u b0 = pkh_add(g0, g2), b1 = pkh_sub(g0, g2);
    h2u b2 = pkh_add(g1, g3), b3 = pkh_sub(g1, g3);
    X[0] = pkh_add(b0, b2);
    X[2] = pkh_sub(b0, b2);
    X[1] = pkh_addmi(b1, b3);   // b1 - i*b3
    X[3] = pkh_addpi(b1, b3);   // b1 + i*b3
}

// One 1024-thread workgroup per image. f16 row-pair FFTs -> half2 LDS tile
// [kx][y^(kx&28)] -> f16 column FFTs -> f32 |F|^2 via fma_mix -> scan binning -> loss.
__global__ __launch_bounds__(1024)
void k_fused(const float* __restrict__ pred, const int4* __restrict__ tbl,
             const int* __restrict__ cnt, const float* __restrict__ mean_cl,
             const float* __restrict__ weighting, float* __restrict__ out,
             float cscale, float invB64) {
    __shared__ __align__(16) unsigned tile[129 * 256];   // half2 as u32, 132096 B
    __shared__ __align__(16) float pbuf[16][260];        // per-wave scan buffer
    const int tid = threadIdx.x, w = tid >> 6, L = tid & 63;
    const int rL = brev6(L);
    const float PI2 = 6.283185307179586f;

    XTH T;
    {
        auto stw = [&](int d, h2u& ta, h2u& tb, h2u& sg) {
            const float s = (L & d) ? -1.f : 1.f;
            const int e = (L & d) ? (L & (d-1)) * (32/d) : 0;
            float ss, cc; __sincosf(-PI2 * (float)e / 64.f, &ss, &cc);
            ta = f2h(cc, ss); tb = f2h(-ss, ss); sg = f2h(s, s);
        };
        stw(32, T.ta32, T.tb32, T.sg32);
        stw(16, T.ta16, T.tb16, T.sg16);
        stw( 8, T.ta8,  T.tb8,  T.sg8);
        stw( 4, T.ta4,  T.tb4,  T.sg4);
        stw( 2, T.ta2,  T.tb2,  T.sg2);
        const float s1 = (L & 1) ? -1.f : 1.f;
        T.sg1 = f2h(s1, s1);
        float sg, cg;
        __sincosf(-PI2 * (float)rL / 256.f, &sg, &cg);
        const float w2x = cg*cg - sg*sg, w2y = 2.f*cg*sg;
        const float w3x = w2x*cg - w2y*sg, w3y = w2x*sg + w2y*cg;
        T.wa1 = f2h(cg, sg);   T.wb1 = f2h(-sg, sg);
        T.wa2 = f2h(w2x, w2y); T.wb2 = f2h(-w2y, w2y);
        T.wa3 = f2h(w3x, w3y); T.wb3 = f2h(-w3y, w3y);
        T.pl = brev6((64 - rL) & 63);
    }

    // ---------------- row phase: 8 row-pairs per wave ----------------
    const float* base = pred + (size_t)blockIdx.x * 65536;
    const int sw = rL & 28;
    #pragma unroll 4
    for (int t = 0; t < 8; ++t) {
        const int y = 16*w + 2*t;
        const float4 ra = *(const float4*)(base + (size_t)y*256 + 4*L);
        const float4 rb = *(const float4*)(base + (size_t)(y+1)*256 + 4*L);
        h2u z[4] = { f2h(ra.x, rb.x), f2h(ra.y, rb.y), f2h(ra.z, rb.z), f2h(ra.w, rb.w) };
        fft64x4h(z, T);                 // packed-FFT Z at kx=brev(L)+64q
        h2u X[4]; twdft4h(z, T, X);
        // Hermitian unpack partners: conj(Z[256-kx]) — one 32-bit shuffle each
        h2u q0 = __float_as_uint(__shfl(__uint_as_float(X[3]), T.pl));
        h2u q1 = __float_as_uint(__shfl(__uint_as_float(X[2]), T.pl));
        if (L == 0) { q0 = X[0]; q1 = X[3]; }   // kx=0 and kx=64 fixes
        const int yi = y ^ sw;                   // y even, sw low2=0 -> +1 ok
        {   // kx = rL:  F_y = 0.5(A+conj(q)),  F_{y+1} = -0.5i(A-conj(q))
            const h2u F = pkh_fma(q0, C_PM, pkh_mul(X[0], C_PP));
            const h2u G = pkh_fma_sw0(q0, C_PP, pkh_mul_sw0(X[0], C_PM));
            uint2 pk; pk.x = F; pk.y = G;
            *(uint2*)&tile[rL*256 + yi] = pk;
        }
        {   // kx = 64 + rL  (same swizzle: (64+rL)&28 == rL&28)
            const h2u F = pkh_fma(q1, C_PM, pkh_mul(X[1], C_PP));
            const h2u G = pkh_fma_sw0(q1, C_PP, pkh_mul_sw0(X[1], C_PM));
            uint2 pk; pk.x = F; pk.y = G;
            *(uint2*)&tile[(64+rL)*256 + yi] = pk;
        }
        if (L == 0) {   // kx = 128: Z[128] self-conjugate -> rows get (Re,0),(Im,0)
            uint2 pk; pk.x = X[2] & 0xFFFFu; pk.y = X[2] >> 16;
            *(uint2*)&tile[128*256 + y] = pk;
        }
    }
    __syncthreads();

    // ---------------- column phase: kx = w + 16t ----------------
    float acc = 0.f;                   // lane accumulates bin (L+1)
    float* pb = pbuf[w];
    const float zf = 0.0f;
    if (L == 0) pb[256] = 0.f;         // sentinel (float4 stores cover 0..255 only)
    #pragma unroll 2
    for (int kx = w; kx <= 128; kx += 16) {
        const int cs = kx & 28;
        const int4 tb = tbl[kx*64 + L];  // <=2 ky-runs as prefix indices (early issue)
        const uint4 uu = *(const uint4*)&tile[kx*256 + ((4*L) ^ cs)];
        h2u z[4] = { uu.x, uu.y, uu.z, uu.w };   // x[4L+a] directly (f16)
        fft64x4h(z, T);
        h2u X[4]; twdft4h(z, T, X);    // X[q] = F[ky = brev(L) + 64q]
        float p0, p1, p2, p3;          // |F|^2 in f32 straight from f16 halves
        #define POW2(P, XS)                                                     \
            asm("v_fma_mix_f32 %0, %2, %2, %1 op_sel:[0,0,0] op_sel_hi:[1,1,0]" \
                : "=v"(P) : "v"(zf), "v"(XS));                                  \
            asm("v_fma_mix_f32 %0, %1, %1, %0 op_sel:[1,1,0] op_sel_hi:[1,1,0]" \
                : "+v"(P) : "v"(XS));
        POW2(p0, X[0]) POW2(p1, X[1]) POW2(p2, X[2]) POW2(p3, X[3])
        #undef POW2
        pb[rL]       = p0;             // natural-order scatter
        pb[rL + 64]  = p1;
        pb[rL + 128] = p2;
        pb[rL + 192] = p3;
        const float4 pv = ((const float4*)pb)[L];
        const float s0 = pv.x, s1 = s0+pv.y, s2 = s1+pv.z, s3 = s2+pv.w;
        const float x = dpp_scan64(s3, L);          // inclusive scan of lane totals
        const float ex = x - s3;       // exclusive prefix of the lane's 4-group
        ((float4*)pb)[L] = make_float4(ex+s0, ex+s1, ex+s2, ex+s3);
        const float csum = pb[tb.y] - pb[tb.x] + pb[tb.w] - pb[tb.z];
        const float symw = (kx == 0 || kx == 128) ? 1.f : 2.f;
        acc = fmaf(symw, csum, acc);
    }
    __syncthreads();

    // ---------------- reduce 16 waves, per-image loss ----------------
    float* bins = (float*)tile;        // tile dead now
    bins[w*64 + L] = acc;
    __syncthreads();
    if (tid < 64) {
        float tot = 0.f;
        #pragma unroll
        for (int ww = 0; ww < 16; ++ww) tot += bins[ww*64 + tid];
        const int c = cnt[tid + 1];
        const float inv = (c > 0) ? 1.0f / (float)c : 0.0f;
        const float v = tot * cscale * inv;
        const float d = logf(v + 1e-12f) - logf(mean_cl[tid] + 1e-12f);
        float l = weighting[tid] * d * d;
        #pragma unroll
        for (int o = 32; o; o >>= 1) l += __shfl_down(l, o);
        if (tid == 0) atomicAdd(out, l * invB64);
    }
}

// Prep: one block per kx row (0..255). All rows: per-segment counts. Rows
// 0..128 additionally emit the boundary table (<=2 contiguous ky-runs as
// prefix-lookup indices; 256 = zero sentinel slot).
__global__ __launch_bounds__(256) void k_prep(const int* __restrict__ seg,
                                              int4* __restrict__ tbl,
                                              int* __restrict__ cnt) {
    __shared__ int lo1[NSEG], hi1[NSEG], lo2[NSEG], hi2[NSEG], lc[NSEG];
    const int kx = blockIdx.x, ky = threadIdx.x;
    if (ky < NSEG) { lo1[ky] = 300; hi1[ky] = -1; lo2[ky] = 300; hi2[ky] = -1; lc[ky] = 0; }
    __syncthreads();
    const int s = seg[kx * 256 + ky];
    atomicAdd(&lc[s], 1);
    if (kx <= 128) {
        if (ky <= 128) { atomicMin(&lo1[s], ky); atomicMax(&hi1[s], ky); }
        else           { atomicMin(&lo2[s], ky); atomicMax(&hi2[s], ky); }
    }
    __syncthreads();
    if (ky < NSEG && lc[ky] > 0) atomicAdd(&cnt[ky], lc[ky]);
    if (kx <= 128 && ky >= 1 && ky <= 64) {
        int4 t;
        if (hi1[ky] < 0) { t.x = 256; t.y = 256; }
        else             { t.x = (lo1[ky] > 0) ? lo1[ky] - 1 : 256; t.y = hi1[ky]; }
        if (hi2[ky] < 0) { t.z = 256; t.w = 256; }
        else             { t.z = lo2[ky] - 1; t.w = hi2[ky]; }
        tbl[kx * 64 + (ky - 1)] = t;
    }
}

extern "C" void kernel_launch(void* const* d_in, const int* in_sizes, int n_in,
                              void* d_out, int out_size, void* d_ws, size_t ws_size,
                              hipStream_t stream) {
    const float* pred      = (const float*)d_in[0];
    const float* mean_cl   = (const float*)d_in[1];
    const float* weighting = (const float*)d_in[2];
    const int*   seg       = (const int*)d_in[3];
    float* out = (float*)d_out;

    const int B = in_sizes[0] / 65536;

    // ws: [cnt 66 i32, pad to 256B][boundary table 129*64 int4]
    int*  cnt = (int*)d_ws;
    int4* tbl = (int4*)((char*)d_ws + 256);

    const double rad = (5.0 * 60.0 / 256.0) * M_PI / 180.0;
    const float cscale = (float)(rad * rad / (65536.0 * 1e12)); // rad^2/N^2/TSZ^2
    const float invB64 = (float)(1.0 / ((double)B * 64.0));

    hipMemsetAsync(d_out, 0, sizeof(float), stream);
    hipMemsetAsync(cnt, 0, NSEG * sizeof(int), stream);
    k_prep<<<256, 256, 0, stream>>>(seg, tbl, cnt);
    k_fused<<<B, 1024, 0, stream>>>(pred, tbl, cnt, mean_cl, weighting,
                                    out, cscale, invB64);
}

// Round 16
// 115.226 us; speedup vs baseline: 1.1439x; 1.0565x over previous
//
#include <hip/hip_runtime.h>
#include <hip/hip_fp16.h>
#include <math.h>

#define NSEG 66                 // segments 0..65; valid bins 1..64
typedef unsigned uv2 __attribute__((ext_vector_type(2)));
typedef unsigned h2u;           // half2 bit pattern: lo = re, hi = im

__device__ __forceinline__ int brev6(int l) {
    return ((l&1)<<5)|((l&2)<<3)|((l&4)<<1)|((l&8)>>1)|((l&16)>>3)|((l&32)>>5);
}
__device__ __forceinline__ h2u f2h(float a, float b) {
    __half2 h = __floats2half2_rn(a, b); return *reinterpret_cast<unsigned*>(&h);
}
__device__ __forceinline__ h2u shflu(h2u x, int src) {
    return __float_as_uint(__shfl(__uint_as_float(x), src));
}

// ---------------- packed f16 primitives (VOP3P, one VGPR per complex) ----------------
__device__ __forceinline__ h2u pkh_fma(h2u a, h2u b, h2u c) {   // a*b + c (per half)
    h2u d; asm("v_pk_fma_f16 %0, %1, %2, %3" : "=v"(d) : "v"(a), "v"(b), "v"(c));
    return d;
}
__device__ __forceinline__ h2u pkh_mul(h2u a, h2u b) {
    h2u d; asm("v_pk_mul_f16 %0, %1, %2" : "=v"(d) : "v"(a), "v"(b));
    return d;
}
__device__ __forceinline__ h2u pkh_add(h2u a, h2u b) {
    h2u d; asm("v_pk_add_f16 %0, %1, %2" : "=v"(d) : "v"(a), "v"(b));
    return d;
}
__device__ __forceinline__ h2u pkh_sub(h2u a, h2u b) {
    h2u d; asm("v_pk_add_f16 %0, %1, %2 neg_lo:[0,1] neg_hi:[0,1]" : "=v"(d) : "v"(a), "v"(b));
    return d;
}
__device__ __forceinline__ h2u pkh_addmi(h2u a, h2u b) {  // a - i*b = (a.lo+b.hi, a.hi-b.lo)
    h2u d; asm("v_pk_add_f16 %0, %1, %2 op_sel:[0,1] op_sel_hi:[1,0] neg_hi:[0,1]"
               : "=v"(d) : "v"(a), "v"(b));
    return d;
}
__device__ __forceinline__ h2u pkh_addpi(h2u a, h2u b) {  // a + i*b = (a.lo-b.hi, a.hi+b.lo)
    h2u d; asm("v_pk_add_f16 %0, %1, %2 op_sel:[0,1] op_sel_hi:[1,0] neg_lo:[0,1]"
               : "=v"(d) : "v"(a), "v"(b));
    return d;
}
// complex mul: z=(x,y), ta=(c,s), tb=(-s,s) -> (xc - ys, xs + yc)
__device__ __forceinline__ h2u cmulh(h2u z, h2u ta, h2u tb) {
    h2u p, r;
    asm("v_pk_mul_f16 %0, %1, %2 op_sel:[0,0] op_sel_hi:[1,0]" : "=v"(p) : "v"(z), "v"(ta));
    asm("v_pk_fma_f16 %0, %1, %2, %3 op_sel:[1,0,0] op_sel_hi:[0,1,1]"
        : "=v"(r) : "v"(z), "v"(tb), "v"(p));
    return r;
}
// swapped-src0 variants for the Hermitian unpack
__device__ __forceinline__ h2u pkh_mul_sw0(h2u a, h2u b) {  // (a.hi*b.lo, a.lo*b.hi)
    h2u d; asm("v_pk_mul_f16 %0, %1, %2 op_sel:[1,0] op_sel_hi:[0,1]" : "=v"(d) : "v"(a), "v"(b));
    return d;
}
__device__ __forceinline__ h2u pkh_fma_sw0(h2u a, h2u b, h2u c) { // (a.hi*b.lo+c.lo, a.lo*b.hi+c.hi)
    h2u d; asm("v_pk_fma_f16 %0, %1, %2, %3 op_sel:[1,0,0] op_sel_hi:[0,1,1]"
               : "=v"(d) : "v"(a), "v"(b), "v"(c));
    return d;
}
// |X|^2 in f32 straight from f16 halves
__device__ __forceinline__ float pow2h(h2u X) {
    float p; const float zf = 0.f;
    asm("v_fma_mix_f32 %0, %2, %2, %1 op_sel:[0,0,0] op_sel_hi:[1,1,0]" : "=v"(p) : "v"(zf), "v"(X));
    asm("v_fma_mix_f32 %0, %1, %1, %0 op_sel:[1,1,0] op_sel_hi:[1,1,0]" : "+v"(p) : "v"(X));
    return p;
}
// byte permute: sel byte <4 -> lo bytes, 4..7 -> hi bytes
__device__ __forceinline__ unsigned bperm(unsigned hi, unsigned lo, unsigned sel) {
#if __has_builtin(__builtin_amdgcn_perm)
    return __builtin_amdgcn_perm(hi, lo, sel);
#else
    unsigned long long v = ((unsigned long long)hi << 32) | lo;
    unsigned r = 0;
    for (int b = 0; b < 4; ++b) r |= ((unsigned)(v >> (8*((sel>>(8*b))&7))) & 0xFF) << (8*b);
    return r;
#endif
}

#define C_PP 0x38003800u    // half2 ( 0.5,  0.5)
#define C_PM 0xB8003800u    // half2 ( 0.5, -0.5)

// Per-lane constants (all f16-packed, one VGPR each).
struct XTH {
    h2u ta32, tb32, sg32;
    h2u ta16, tb16, sg16;
    h2u ta8,  tb8,  sg8;
    h2u ta4,  tb4,  sg4;
    h2u ta2,  tb2,  sg2;
    h2u sg1;
    h2u wa1, wb1, wa2, wb2, wa3, wb3;   // W256^{brev(L)},^2,^3
    int pl;                             // Hermitian partner lane
};

// ---- cross-lane exchange + packed butterfly ----
__device__ __forceinline__ h2u bflyh_pl32(h2u z, h2u sg, h2u ta, h2u tb) {
#if __has_builtin(__builtin_amdgcn_permlane32_swap)
    uv2 r = __builtin_amdgcn_permlane32_swap(z, z, false, false);
    h2u u = pkh_fma(r[1], sg, r[0]);
#else
    h2u c = __float_as_uint(__shfl_xor(__uint_as_float(z), 32));
    h2u u = pkh_fma(z, sg, c);
#endif
    return cmulh(u, ta, tb);
}
__device__ __forceinline__ h2u bflyh_pl16(h2u z, h2u sg, h2u ta, h2u tb) {
#if __has_builtin(__builtin_amdgcn_permlane16_swap)
    uv2 r = __builtin_amdgcn_permlane16_swap(z, z, false, false);
    h2u u = pkh_fma(r[1], sg, r[0]);
#else
    h2u c = __float_as_uint(__shfl_xor(__uint_as_float(z), 16));
    h2u u = pkh_fma(z, sg, c);
#endif
    return cmulh(u, ta, tb);
}
template<int CTRL>
__device__ __forceinline__ h2u dppx(h2u x) {
#if __has_builtin(__builtin_amdgcn_update_dpp)
    return (h2u)__builtin_amdgcn_update_dpp((int)x, (int)x, CTRL, 0xF, 0xF, false);
#else
    const int d = (CTRL == 0x128) ? 8 : (CTRL == 0x4E ? 2 : 1);
    return __float_as_uint(__shfl_xor(__uint_as_float(x), d));
#endif
}
template<int CTRL>
__device__ __forceinline__ h2u bflyh_dpp(h2u z, h2u sg, h2u ta, h2u tb) {
    return cmulh(pkh_fma(z, sg, dppx<CTRL>(z)), ta, tb);
}
__device__ __forceinline__ h2u bflyh1(h2u z, h2u sg) {   // d=1, tw==1
    return pkh_fma(z, sg, dppx<0xB1>(z));
}
// d=4 on the DS pipe: ds_swizzle BitMode xor4 = 0x101F (DS overlaps free; VALU is scarce)
__device__ __forceinline__ h2u bflyh_ds4(h2u z, h2u sg, h2u ta, h2u tb) {
    h2u c = (h2u)__builtin_amdgcn_ds_swizzle((int)z, 0x101F);
    return cmulh(pkh_fma(z, sg, c), ta, tb);
}

// 64-lane inclusive prefix sum on the VALU (DPP scan), f32.
__device__ __forceinline__ float dpp_scan64(float x, int L) {
#if __has_builtin(__builtin_amdgcn_update_dpp)
    #define UPD(ctrl, rmask) __int_as_float(__builtin_amdgcn_update_dpp( \
        0, __float_as_int(x), ctrl, rmask, 0xF, false))
    x += UPD(0x111, 0xF);   // row_shr:1
    x += UPD(0x112, 0xF);   // row_shr:2
    x += UPD(0x114, 0xF);   // row_shr:4
    x += UPD(0x118, 0xF);   // row_shr:8
    x += UPD(0x142, 0xA);   // row_bcast:15 -> rows 1,3
    x += UPD(0x143, 0xC);   // row_bcast:31 -> rows 2,3
    #undef UPD
    return x;
#else
    #pragma unroll
    for (int off = 1; off < 64; off <<= 1) {
        const float yv = __shfl_up(x, off);
        if (L >= off) x += yv;
    }
    return x;
#endif
}

// Four independent 64-pt FFTs in f16; result at lane L is G[brev6(L)].
__device__ __forceinline__ void fft64x4h(h2u z[4], const XTH& T) {
    #pragma unroll
    for (int a = 0; a < 4; ++a) {
        z[a] = bflyh_pl32(z[a], T.sg32, T.ta32, T.tb32);
        z[a] = bflyh_pl16(z[a], T.sg16, T.ta16, T.tb16);
        z[a] = bflyh_dpp<0x128>(z[a], T.sg8, T.ta8, T.tb8);
        z[a] = bflyh_ds4(z[a], T.sg4, T.ta4, T.tb4);
        z[a] = bflyh_dpp<0x4E>(z[a], T.sg2, T.ta2, T.tb2);
        z[a] = bflyh1(z[a], T.sg1);
    }
}
// Twiddle by W256^{a*brev(L)} then in-lane DFT4: X[q] = F[brev6(L) + 64q].
__device__ __forceinline__ void twdft4h(const h2u z[4], const XTH& T, h2u X[4]) {
    h2u g0 = z[0];
    h2u g1 = cmulh(z[1], T.wa1, T.wb1);
    h2u g2 = cmulh(z[2], T.wa2, T.wb2);
    h2u g3 = cmulh(z[3], T.wa3, T.wb3);
    h2u b0 = pkh_add(g0, g2), b1 = pkh_sub(g0, g2);
    h2u b2 = pkh_add(g1, g3), b3 = pkh_sub(g1, g3);
    X[0] = pkh_add(b0, b2);
    X[2] = pkh_sub(b0, b2);
    X[1] = pkh_addmi(b1, b3);   // b1 - i*b3
    X[3] = pkh_addpi(b1, b3);   // b1 + i*b3
}

// One 1024-thread workgroup per image. f16 row-pair FFTs -> half2 LDS tile
// (128 rows: row 0 = packed real columns {0,128}; rows 1..127 = kx) -> f16
// column FFTs (128 = exactly 8/wave) -> f32 |F|^2 -> scan binning -> loss.
__global__ __launch_bounds__(1024)
void k_fused(const float* __restrict__ pred, const int4* __restrict__ tbl,
             const int* __restrict__ cnt, const float* __restrict__ mean_cl,
             const float* __restrict__ weighting, float* __restrict__ out,
             float cscale, float invB64) {
    __shared__ __align__(16) unsigned tile[128 * 256];   // half2 as u32, 131072 B
    __shared__ __align__(16) float pbuf[16][260];        // per-wave scan buffer
    const int tid = threadIdx.x, w = tid >> 6, L = tid & 63;
    const int rL = brev6(L);
    const float PI2 = 6.283185307179586f;

    XTH T;
    {
        auto stw = [&](int d, h2u& ta, h2u& tb, h2u& sg) {
            const float s = (L & d) ? -1.f : 1.f;
            const int e = (L & d) ? (L & (d-1)) * (32/d) : 0;
            float ss, cc; __sincosf(-PI2 * (float)e / 64.f, &ss, &cc);
            ta = f2h(cc, ss); tb = f2h(-ss, ss); sg = f2h(s, s);
        };
        stw(32, T.ta32, T.tb32, T.sg32);
        stw(16, T.ta16, T.tb16, T.sg16);
        stw( 8, T.ta8,  T.tb8,  T.sg8);
        stw( 4, T.ta4,  T.tb4,  T.sg4);
        stw( 2, T.ta2,  T.tb2,  T.sg2);
        const float s1 = (L & 1) ? -1.f : 1.f;
        T.sg1 = f2h(s1, s1);
        float sg, cg;
        __sincosf(-PI2 * (float)rL / 256.f, &sg, &cg);
        const float w2x = cg*cg - sg*sg, w2y = 2.f*cg*sg;
        const float w3x = w2x*cg - w2y*sg, w3y = w2x*sg + w2y*cg;
        T.wa1 = f2h(cg, sg);   T.wb1 = f2h(-sg, sg);
        T.wa2 = f2h(w2x, w2y); T.wb2 = f2h(-w2y, w2y);
        T.wa3 = f2h(w3x, w3y); T.wb3 = f2h(-w3y, w3y);
        T.pl = brev6((64 - rL) & 63);
    }

    // ---------------- row phase: 8 row-pairs per wave ----------------
    const float* base = pred + (size_t)blockIdx.x * 65536;
    const int sw = rL & 28;
    #pragma unroll 4
    for (int t = 0; t < 8; ++t) {
        const int y = 16*w + 2*t;
        const float4 ra = *(const float4*)(base + (size_t)y*256 + 4*L);
        const float4 rb = *(const float4*)(base + (size_t)(y+1)*256 + 4*L);
        h2u z[4] = { f2h(ra.x, rb.x), f2h(ra.y, rb.y), f2h(ra.z, rb.z), f2h(ra.w, rb.w) };
        fft64x4h(z, T);                 // packed-FFT Z at kx=brev(L)+64q
        h2u X[4]; twdft4h(z, T, X);
        // Hermitian unpack partners: conj(Z[256-kx]) — one 32-bit shuffle each
        h2u q0 = shflu(X[3], T.pl);
        h2u q1 = shflu(X[2], T.pl);
        if (L == 0) { q0 = X[0]; q1 = X[3]; }   // kx=0 and kx=64 fixes
        const int yi = y ^ sw;                   // y even, sw low2=0 -> +1 ok
        {   // kx = rL:  F_y = 0.5(A+conj(q)),  F_{y+1} = -0.5i(A-conj(q))
            const h2u F = pkh_fma(q0, C_PM, pkh_mul(X[0], C_PP));
            const h2u G = pkh_fma_sw0(q0, C_PP, pkh_mul_sw0(X[0], C_PM));
            uint2 pk;
            if (L == 0) {
                // packed row 0: (F0[y], F128[y]) and (F0[y+1], F128[y+1]);
                // F0[y]=F.lo, F0[y+1]=G.lo, F128[y]=X2.lo, F128[y+1]=X2.hi
                pk.x = bperm(X[2], F, 0x05040100u);
                pk.y = bperm(X[2], G, 0x07060100u);
            } else {
                pk.x = F; pk.y = G;
            }
            *(uint2*)&tile[rL*256 + yi] = pk;
        }
        {   // kx = 64 + rL  (same swizzle: (64+rL)&28 == rL&28)
            const h2u F = pkh_fma(q1, C_PM, pkh_mul(X[1], C_PP));
            const h2u G = pkh_fma_sw0(q1, C_PP, pkh_mul_sw0(X[1], C_PM));
            uint2 pk; pk.x = F; pk.y = G;
            *(uint2*)&tile[(64+rL)*256 + yi] = pk;
        }
    }
    __syncthreads();

    // ---------------- column phase: p = w + 16t, 8 cols per wave ----------------
    float acc = 0.f;                   // lane accumulates bin (L+1)
    float* pb = pbuf[w];
    if (L == 0) pb[256] = 0.f;         // sentinel (float4 stores cover 0..255 only)
    auto binpass = [&](float p0, float p1, float p2, float p3, int4 tb) -> float {
        pb[rL] = p0; pb[rL+64] = p1; pb[rL+128] = p2; pb[rL+192] = p3;
        const float4 pv = ((const float4*)pb)[L];
        const float s0 = pv.x, s1 = s0+pv.y, s2 = s1+pv.z, s3 = s2+pv.w;
        const float x = dpp_scan64(s3, L);
        const float ex = x - s3;
        ((float4*)pb)[L] = make_float4(ex+s0, ex+s1, ex+s2, ex+s3);
        return pb[tb.y] - pb[tb.x] + pb[tb.w] - pb[tb.z];
    };
    #pragma unroll 2
    for (int kx = w; kx <= 127; kx += 16) {
        const int cs = kx & 28;
        const uint4 uu = *(const uint4*)&tile[kx*256 + ((4*L) ^ cs)];
        h2u z[4] = { uu.x, uu.y, uu.z, uu.w };   // x[4L+a] directly (f16)
        fft64x4h(z, T);
        h2u X[4]; twdft4h(z, T, X);    // X[q] = C[k = brev(L) + 64q]
        if (kx == 0) {                 // wave 0: packed real columns {0,128}
            h2u Xp0 = shflu(X[3], T.pl), Xp1 = shflu(X[2], T.pl);
            h2u Xp2 = shflu(X[1], T.pl), Xp3 = shflu(X[0], T.pl);
            if (L == 0) { Xp0 = X[0]; Xp1 = X[3]; Xp2 = X[2]; Xp3 = X[1]; }
            // H0 = (C + conj(Cp))/2 (col 0); H128 = -i(C - conj(Cp))/2 (col 128)
            const float a0 = pow2h(pkh_fma(Xp0, C_PM, pkh_mul(X[0], C_PP)));
            const float a1 = pow2h(pkh_fma(Xp1, C_PM, pkh_mul(X[1], C_PP)));
            const float a2 = pow2h(pkh_fma(Xp2, C_PM, pkh_mul(X[2], C_PP)));
            const float a3 = pow2h(pkh_fma(Xp3, C_PM, pkh_mul(X[3], C_PP)));
            const float b0 = pow2h(pkh_fma_sw0(Xp0, C_PP, pkh_mul_sw0(X[0], C_PM)));
            const float b1 = pow2h(pkh_fma_sw0(Xp1, C_PP, pkh_mul_sw0(X[1], C_PM)));
            const float b2 = pow2h(pkh_fma_sw0(Xp2, C_PP, pkh_mul_sw0(X[2], C_PM)));
            const float b3 = pow2h(pkh_fma_sw0(Xp3, C_PP, pkh_mul_sw0(X[3], C_PM)));
            acc += binpass(a0, a1, a2, a3, tbl[0*64 + L]);      // symw = 1
            acc += binpass(b0, b1, b2, b3, tbl[128*64 + L]);    // symw = 1
        } else {
            const int4 tb = tbl[kx*64 + L];
            const float p0 = pow2h(X[0]), p1 = pow2h(X[1]);
            const float p2 = pow2h(X[2]), p3 = pow2h(X[3]);
            acc = fmaf(2.f, binpass(p0, p1, p2, p3, tb), acc);  // kx 1..127: symw = 2
        }
    }
    __syncthreads();

    // ---------------- reduce 16 waves, per-image loss ----------------
    float* bins = (float*)tile;        // tile dead now
    bins[w*64 + L] = acc;
    __syncthreads();
    if (tid < 64) {
        float tot = 0.f;
        #pragma unroll
        for (int ww = 0; ww < 16; ++ww) tot += bins[ww*64 + tid];
        const int c = cnt[tid + 1];
        const float inv = (c > 0) ? 1.0f / (float)c : 0.0f;
        const float v = tot * cscale * inv;
        const float d = logf(v + 1e-12f) - logf(mean_cl[tid] + 1e-12f);
        float l = weighting[tid] * d * d;
        #pragma unroll
        for (int o = 32; o; o >>= 1) l += __shfl_down(l, o);
        if (tid == 0) atomicAdd(out, l * invB64);
    }
}

// Prep: one block per kx row (0..255). All rows: per-segment counts. Rows
// 0..128 additionally emit the boundary table (<=2 contiguous ky-runs as
// prefix-lookup indices; 256 = zero sentinel slot).
__global__ __launch_bounds__(256) void k_prep(const int* __restrict__ seg,
                                              int4* __restrict__ tbl,
                                              int* __restrict__ cnt) {
    __shared__ int lo1[NSEG], hi1[NSEG], lo2[NSEG], hi2[NSEG], lc[NSEG];
    const int kx = blockIdx.x, ky = threadIdx.x;
    if (ky < NSEG) { lo1[ky] = 300; hi1[ky] = -1; lo2[ky] = 300; hi2[ky] = -1; lc[ky] = 0; }
    __syncthreads();
    const int s = seg[kx * 256 + ky];
    atomicAdd(&lc[s], 1);
    if (kx <= 128) {
        if (ky <= 128) { atomicMin(&lo1[s], ky); atomicMax(&hi1[s], ky); }
        else           { atomicMin(&lo2[s], ky); atomicMax(&hi2[s], ky); }
    }
    __syncthreads();
    if (ky < NSEG && lc[ky] > 0) atomicAdd(&cnt[ky], lc[ky]);
    if (kx <= 128 && ky >= 1 && ky <= 64) {
        int4 t;
        if (hi1[ky] < 0) { t.x = 256; t.y = 256; }
        else             { t.x = (lo1[ky] > 0) ? lo1[ky] - 1 : 256; t.y = hi1[ky]; }
        if (hi2[ky] < 0) { t.z = 256; t.w = 256; }
        else             { t.z = lo2[ky] - 1; t.w = hi2[ky]; }
        tbl[kx * 64 + (ky - 1)] = t;
    }
}

extern "C" void kernel_launch(void* const* d_in, const int* in_sizes, int n_in,
                              void* d_out, int out_size, void* d_ws, size_t ws_size,
                              hipStream_t stream) {
    const float* pred      = (const float*)d_in[0];
    const float* mean_cl   = (const float*)d_in[1];
    const float* weighting = (const float*)d_in[2];
    const int*   seg       = (const int*)d_in[3];
    float* out = (float*)d_out;

    const int B = in_sizes[0] / 65536;

    // ws: [cnt 66 i32, pad to 256B][boundary table 129*64 int4]
    int*  cnt = (int*)d_ws;
    int4* tbl = (int4*)((char*)d_ws + 256);

    const double rad = (5.0 * 60.0 / 256.0) * M_PI / 180.0;
    const float cscale = (float)(rad * rad / (65536.0 * 1e12)); // rad^2/N^2/TSZ^2
    const float invB64 = (float)(1.0 / ((double)B * 64.0));

    hipMemsetAsync(d_out, 0, sizeof(float), stream);
    hipMemsetAsync(cnt, 0, NSEG * sizeof(int), stream);
    k_prep<<<256, 256, 0, stream>>>(seg, tbl, cnt);
    k_fused<<<B, 1024, 0, stream>>>(pred, tbl, cnt, mean_cl, weighting,
                                    out, cscale, invB64);
}

// Round 17
// 113.699 us; speedup vs baseline: 1.1592x; 1.0134x over previous
//
#include <hip/hip_runtime.h>
#include <hip/hip_fp16.h>
#include <math.h>

#define NSEG 66                 // segments 0..65; valid bins 1..64
typedef unsigned uv2 __attribute__((ext_vector_type(2)));
typedef unsigned h2u;           // half2 bit pattern: lo = re, hi = im

__device__ __forceinline__ int brev6(int l) {
    return ((l&1)<<5)|((l&2)<<3)|((l&4)<<1)|((l&8)>>1)|((l&16)>>3)|((l&32)>>5);
}
__device__ __forceinline__ h2u f2h(float a, float b) {
    __half2 h = __floats2half2_rn(a, b); return *reinterpret_cast<unsigned*>(&h);
}
__device__ __forceinline__ h2u shflu(h2u x, int src) {
    return __float_as_uint(__shfl(__uint_as_float(x), src));
}

// ---------------- packed f16 primitives (VOP3P, one VGPR per complex) ----------------
__device__ __forceinline__ h2u pkh_fma(h2u a, h2u b, h2u c) {   // a*b + c (per half)
    h2u d; asm("v_pk_fma_f16 %0, %1, %2, %3" : "=v"(d) : "v"(a), "v"(b), "v"(c));
    return d;
}
__device__ __forceinline__ h2u pkh_mul(h2u a, h2u b) {
    h2u d; asm("v_pk_mul_f16 %0, %1, %2" : "=v"(d) : "v"(a), "v"(b));
    return d;
}
__device__ __forceinline__ h2u pkh_add(h2u a, h2u b) {
    h2u d; asm("v_pk_add_f16 %0, %1, %2" : "=v"(d) : "v"(a), "v"(b));
    return d;
}
__device__ __forceinline__ h2u pkh_sub(h2u a, h2u b) {
    h2u d; asm("v_pk_add_f16 %0, %1, %2 neg_lo:[0,1] neg_hi:[0,1]" : "=v"(d) : "v"(a), "v"(b));
    return d;
}
__device__ __forceinline__ h2u pkh_addmi(h2u a, h2u b) {  // a - i*b = (a.lo+b.hi, a.hi-b.lo)
    h2u d; asm("v_pk_add_f16 %0, %1, %2 op_sel:[0,1] op_sel_hi:[1,0] neg_hi:[0,1]"
               : "=v"(d) : "v"(a), "v"(b));
    return d;
}
__device__ __forceinline__ h2u pkh_addpi(h2u a, h2u b) {  // a + i*b = (a.lo-b.hi, a.hi+b.lo)
    h2u d; asm("v_pk_add_f16 %0, %1, %2 op_sel:[0,1] op_sel_hi:[1,0] neg_lo:[0,1]"
               : "=v"(d) : "v"(a), "v"(b));
    return d;
}
// complex mul: z=(x,y), ta=(c,s), tb=(-s,s) -> (xc - ys, xs + yc)
__device__ __forceinline__ h2u cmulh(h2u z, h2u ta, h2u tb) {
    h2u p, r;
    asm("v_pk_mul_f16 %0, %1, %2 op_sel:[0,0] op_sel_hi:[1,0]" : "=v"(p) : "v"(z), "v"(ta));
    asm("v_pk_fma_f16 %0, %1, %2, %3 op_sel:[1,0,0] op_sel_hi:[0,1,1]"
        : "=v"(r) : "v"(z), "v"(tb), "v"(p));
    return r;
}
// swapped-src0 variants for the Hermitian unpack
__device__ __forceinline__ h2u pkh_mul_sw0(h2u a, h2u b) {  // (a.hi*b.lo, a.lo*b.hi)
    h2u d; asm("v_pk_mul_f16 %0, %1, %2 op_sel:[1,0] op_sel_hi:[0,1]" : "=v"(d) : "v"(a), "v"(b));
    return d;
}
__device__ __forceinline__ h2u pkh_fma_sw0(h2u a, h2u b, h2u c) { // (a.hi*b.lo+c.lo, a.lo*b.hi+c.hi)
    h2u d; asm("v_pk_fma_f16 %0, %1, %2, %3 op_sel:[1,0,0] op_sel_hi:[0,1,1]"
               : "=v"(d) : "v"(a), "v"(b), "v"(c));
    return d;
}
// |X|^2 in f32 straight from f16 halves
__device__ __forceinline__ float pow2h(h2u X) {
    float p; const float zf = 0.f;
    asm("v_fma_mix_f32 %0, %2, %2, %1 op_sel:[0,0,0] op_sel_hi:[1,1,0]" : "=v"(p) : "v"(zf), "v"(X));
    asm("v_fma_mix_f32 %0, %1, %1, %0 op_sel:[1,1,0] op_sel_hi:[1,1,0]" : "+v"(p) : "v"(X));
    return p;
}
// byte permute: sel byte <4 -> lo bytes, 4..7 -> hi bytes
__device__ __forceinline__ unsigned bperm(unsigned hi, unsigned lo, unsigned sel) {
#if __has_builtin(__builtin_amdgcn_perm)
    return __builtin_amdgcn_perm(hi, lo, sel);
#else
    unsigned long long v = ((unsigned long long)hi << 32) | lo;
    unsigned r = 0;
    for (int b = 0; b < 4; ++b) r |= ((unsigned)(v >> (8*((sel>>(8*b))&7))) & 0xFF) << (8*b);
    return r;
#endif
}

#define C_PP 0x38003800u    // half2 ( 0.5,  0.5)
#define C_PM 0xB8003800u    // half2 ( 0.5, -0.5)

// Per-lane constants (all f16-packed, one VGPR each).
struct XTH {
    h2u ta32, tb32, sg32;
    h2u ta16, tb16, sg16;
    h2u ta8,  tb8,  sg8;
    h2u ta4,  tb4,  sg4;
    h2u ta2,  tb2,  sg2;
    h2u sg1;
    h2u wa1, wb1, wa2, wb2, wa3, wb3;   // W256^{brev(L)},^2,^3
    int pl;                             // Hermitian partner lane
};

// ---- cross-lane exchange + packed butterfly ----
__device__ __forceinline__ h2u bflyh_pl32(h2u z, h2u sg, h2u ta, h2u tb) {
#if __has_builtin(__builtin_amdgcn_permlane32_swap)
    uv2 r = __builtin_amdgcn_permlane32_swap(z, z, false, false);
    h2u u = pkh_fma(r[1], sg, r[0]);
#else
    h2u c = __float_as_uint(__shfl_xor(__uint_as_float(z), 32));
    h2u u = pkh_fma(z, sg, c);
#endif
    return cmulh(u, ta, tb);
}
__device__ __forceinline__ h2u bflyh_pl16(h2u z, h2u sg, h2u ta, h2u tb) {
#if __has_builtin(__builtin_amdgcn_permlane16_swap)
    uv2 r = __builtin_amdgcn_permlane16_swap(z, z, false, false);
    h2u u = pkh_fma(r[1], sg, r[0]);
#else
    h2u c = __float_as_uint(__shfl_xor(__uint_as_float(z), 16));
    h2u u = pkh_fma(z, sg, c);
#endif
    return cmulh(u, ta, tb);
}
template<int CTRL>
__device__ __forceinline__ h2u dppx(h2u x) {
#if __has_builtin(__builtin_amdgcn_update_dpp)
    return (h2u)__builtin_amdgcn_update_dpp((int)x, (int)x, CTRL, 0xF, 0xF, false);
#else
    const int d = (CTRL == 0x128) ? 8 : (CTRL == 0x4E ? 2 : 1);
    return __float_as_uint(__shfl_xor(__uint_as_float(x), d));
#endif
}
template<int CTRL>
__device__ __forceinline__ h2u bflyh_dpp(h2u z, h2u sg, h2u ta, h2u tb) {
    return cmulh(pkh_fma(z, sg, dppx<CTRL>(z)), ta, tb);
}
__device__ __forceinline__ h2u bflyh1(h2u z, h2u sg) {   // d=1, tw==1
    return pkh_fma(z, sg, dppx<0xB1>(z));
}
// d=4 on the DS pipe: ds_swizzle BitMode xor4 = 0x101F (DS overlaps free; VALU is scarce)
__device__ __forceinline__ h2u bflyh_ds4(h2u z, h2u sg, h2u ta, h2u tb) {
    h2u c = (h2u)__builtin_amdgcn_ds_swizzle((int)z, 0x101F);
    return cmulh(pkh_fma(z, sg, c), ta, tb);
}

// 64-lane inclusive prefix sum on the VALU (DPP scan), f32.
__device__ __forceinline__ float dpp_scan64(float x, int L) {
#if __has_builtin(__builtin_amdgcn_update_dpp)
    #define UPD(ctrl, rmask) __int_as_float(__builtin_amdgcn_update_dpp( \
        0, __float_as_int(x), ctrl, rmask, 0xF, false))
    x += UPD(0x111, 0xF);   // row_shr:1
    x += UPD(0x112, 0xF);   // row_shr:2
    x += UPD(0x114, 0xF);   // row_shr:4
    x += UPD(0x118, 0xF);   // row_shr:8
    x += UPD(0x142, 0xA);   // row_bcast:15 -> rows 1,3
    x += UPD(0x143, 0xC);   // row_bcast:31 -> rows 2,3
    #undef UPD
    return x;
#else
    #pragma unroll
    for (int off = 1; off < 64; off <<= 1) {
        const float yv = __shfl_up(x, off);
        if (L >= off) x += yv;
    }
    return x;
#endif
}

// N independent 64-pt FFTs in f16; result at lane L is G[brev6(L)].
// N chains of ILP hide the cross-lane hop latency.
template<int N>
__device__ __forceinline__ void fft64xNh(h2u* z, const XTH& T) {
    #pragma unroll
    for (int a = 0; a < N; ++a) {
        z[a] = bflyh_pl32(z[a], T.sg32, T.ta32, T.tb32);
        z[a] = bflyh_pl16(z[a], T.sg16, T.ta16, T.tb16);
        z[a] = bflyh_dpp<0x128>(z[a], T.sg8, T.ta8, T.tb8);
        z[a] = bflyh_ds4(z[a], T.sg4, T.ta4, T.tb4);
        z[a] = bflyh_dpp<0x4E>(z[a], T.sg2, T.ta2, T.tb2);
        z[a] = bflyh1(z[a], T.sg1);
    }
}
// Twiddle by W256^{a*brev(L)} then in-lane DFT4: X[q] = F[brev6(L) + 64q].
__device__ __forceinline__ void twdft4h(const h2u z[4], const XTH& T, h2u X[4]) {
    h2u g0 = z[0];
    h2u g1 = cmulh(z[1], T.wa1, T.wb1);
    h2u g2 = cmulh(z[2], T.wa2, T.wb2);
    h2u g3 = cmulh(z[3], T.wa3, T.wb3);
    h2u b0 = pkh_add(g0, g2), b1 = pkh_sub(g0, g2);
    h2u b2 = pkh_add(g1, g3), b3 = pkh_sub(g1, g3);
    X[0] = pkh_add(b0, b2);
    X[2] = pkh_sub(b0, b2);
    X[1] = pkh_addmi(b1, b3);   // b1 - i*b3
    X[3] = pkh_addpi(b1, b3);   // b1 + i*b3
}

// One 1024-thread workgroup per image. f16 row-pair FFTs -> half2 LDS tile
// (128 rows: row 0 = packed real columns {0,128}; rows 1..127 = kx) -> f16
// column FFTs batched 2-per-iteration (8 ILP chains) -> |F|^2 -> scan binning.
__global__ __launch_bounds__(1024)
void k_fused(const float* __restrict__ pred, const int4* __restrict__ tbl,
             const int* __restrict__ cnt, const float* __restrict__ mean_cl,
             const float* __restrict__ weighting, float* __restrict__ out,
             float cscale, float invB64) {
    __shared__ __align__(16) unsigned tile[128 * 256];   // half2 as u32, 131072 B
    __shared__ __align__(16) float pbuf[16][260];        // per-wave scan buffer
    const int tid = threadIdx.x, w = tid >> 6, L = tid & 63;
    const int rL = brev6(L);
    const float PI2 = 6.283185307179586f;

    XTH T;
    {
        auto stw = [&](int d, h2u& ta, h2u& tb, h2u& sg) {
            const float s = (L & d) ? -1.f : 1.f;
            const int e = (L & d) ? (L & (d-1)) * (32/d) : 0;
            float ss, cc; __sincosf(-PI2 * (float)e / 64.f, &ss, &cc);
            ta = f2h(cc, ss); tb = f2h(-ss, ss); sg = f2h(s, s);
        };
        stw(32, T.ta32, T.tb32, T.sg32);
        stw(16, T.ta16, T.tb16, T.sg16);
        stw( 8, T.ta8,  T.tb8,  T.sg8);
        stw( 4, T.ta4,  T.tb4,  T.sg4);
        stw( 2, T.ta2,  T.tb2,  T.sg2);
        const float s1 = (L & 1) ? -1.f : 1.f;
        T.sg1 = f2h(s1, s1);
        float sg, cg;
        __sincosf(-PI2 * (float)rL / 256.f, &sg, &cg);
        const float w2x = cg*cg - sg*sg, w2y = 2.f*cg*sg;
        const float w3x = w2x*cg - w2y*sg, w3y = w2x*sg + w2y*cg;
        T.wa1 = f2h(cg, sg);   T.wb1 = f2h(-sg, sg);
        T.wa2 = f2h(w2x, w2y); T.wb2 = f2h(-w2y, w2y);
        T.wa3 = f2h(w3x, w3y); T.wb3 = f2h(-w3y, w3y);
        T.pl = brev6((64 - rL) & 63);
    }

    // ---------------- row phase: 8 row-pairs per wave ----------------
    const float* base = pred + (size_t)blockIdx.x * 65536;
    const int sw = rL & 28;
    #pragma unroll 4
    for (int t = 0; t < 8; ++t) {
        const int y = 16*w + 2*t;
        const float4 ra = *(const float4*)(base + (size_t)y*256 + 4*L);
        const float4 rb = *(const float4*)(base + (size_t)(y+1)*256 + 4*L);
        h2u z[4] = { f2h(ra.x, rb.x), f2h(ra.y, rb.y), f2h(ra.z, rb.z), f2h(ra.w, rb.w) };
        fft64xNh<4>(z, T);              // packed-FFT Z at kx=brev(L)+64q
        h2u X[4]; twdft4h(z, T, X);
        // Hermitian unpack partners: conj(Z[256-kx]) — one 32-bit shuffle each
        h2u q0 = shflu(X[3], T.pl);
        h2u q1 = shflu(X[2], T.pl);
        if (L == 0) { q0 = X[0]; q1 = X[3]; }   // kx=0 and kx=64 fixes
        const int yi = y ^ sw;                   // y even, sw low2=0 -> +1 ok
        {   // kx = rL:  F_y = 0.5(A+conj(q)),  F_{y+1} = -0.5i(A-conj(q))
            const h2u F = pkh_fma(q0, C_PM, pkh_mul(X[0], C_PP));
            const h2u G = pkh_fma_sw0(q0, C_PP, pkh_mul_sw0(X[0], C_PM));
            uint2 pk;
            if (L == 0) {
                // packed row 0: (F0[y], F128[y]) and (F0[y+1], F128[y+1]);
                // F0[y]=F.lo, F0[y+1]=G.lo, F128[y]=X2.lo, F128[y+1]=X2.hi
                pk.x = bperm(X[2], F, 0x05040100u);
                pk.y = bperm(X[2], G, 0x07060100u);
            } else {
                pk.x = F; pk.y = G;
            }
            *(uint2*)&tile[rL*256 + yi] = pk;
        }
        {   // kx = 64 + rL  (same swizzle: (64+rL)&28 == rL&28)
            const h2u F = pkh_fma(q1, C_PM, pkh_mul(X[1], C_PP));
            const h2u G = pkh_fma_sw0(q1, C_PP, pkh_mul_sw0(X[1], C_PM));
            uint2 pk; pk.x = F; pk.y = G;
            *(uint2*)&tile[(64+rL)*256 + yi] = pk;
        }
    }
    __syncthreads();

    // ------- column phase: 2 columns per iteration (kxA=w+32t, kxB=kxA+16) -------
    float acc = 0.f;                   // lane accumulates bin (L+1)
    float* pb = pbuf[w];
    if (L == 0) pb[256] = 0.f;         // sentinel (float4 stores cover 0..255 only)
    auto binpass = [&](float p0, float p1, float p2, float p3, int4 tb) -> float {
        pb[rL] = p0; pb[rL+64] = p1; pb[rL+128] = p2; pb[rL+192] = p3;
        const float4 pv = ((const float4*)pb)[L];
        const float s0 = pv.x, s1 = s0+pv.y, s2 = s1+pv.z, s3 = s2+pv.w;
        const float x = dpp_scan64(s3, L);
        const float ex = x - s3;
        ((float4*)pb)[L] = make_float4(ex+s0, ex+s1, ex+s2, ex+s3);
        return pb[tb.y] - pb[tb.x] + pb[tb.w] - pb[tb.z];
    };
    #pragma unroll 1
    for (int t = 0; t < 4; ++t) {
        const int kxA = w + 32*t;             // in [0, 111]
        const int kxB = kxA + 16;             // in [16, 127], never the packed row
        const int4 tbB = tbl[kxB*64 + L];
        const uint4 uA = *(const uint4*)&tile[kxA*256 + ((4*L) ^ (kxA & 28))];
        const uint4 uB = *(const uint4*)&tile[kxB*256 + ((4*L) ^ (kxB & 28))];
        h2u z[8] = { uA.x, uA.y, uA.z, uA.w, uB.x, uB.y, uB.z, uB.w };
        fft64xNh<8>(z, T);                    // 8 independent chains
        h2u XA[4], XB[4];
        twdft4h(z, T, XA);
        twdft4h(z + 4, T, XB);
        if (kxA == 0) {                       // wave 0, t=0: packed real cols {0,128}
            h2u Xp0 = shflu(XA[3], T.pl), Xp1 = shflu(XA[2], T.pl);
            h2u Xp2 = shflu(XA[1], T.pl), Xp3 = shflu(XA[0], T.pl);
            if (L == 0) { Xp0 = XA[0]; Xp1 = XA[3]; Xp2 = XA[2]; Xp3 = XA[1]; }
            // H0 = (C + conj(Cp))/2 (col 0); H128 = -i(C - conj(Cp))/2 (col 128)
            const float a0 = pow2h(pkh_fma(Xp0, C_PM, pkh_mul(XA[0], C_PP)));
            const float a1 = pow2h(pkh_fma(Xp1, C_PM, pkh_mul(XA[1], C_PP)));
            const float a2 = pow2h(pkh_fma(Xp2, C_PM, pkh_mul(XA[2], C_PP)));
            const float a3 = pow2h(pkh_fma(Xp3, C_PM, pkh_mul(XA[3], C_PP)));
            const float b0 = pow2h(pkh_fma_sw0(Xp0, C_PP, pkh_mul_sw0(XA[0], C_PM)));
            const float b1 = pow2h(pkh_fma_sw0(Xp1, C_PP, pkh_mul_sw0(XA[1], C_PM)));
            const float b2 = pow2h(pkh_fma_sw0(Xp2, C_PP, pkh_mul_sw0(XA[2], C_PM)));
            const float b3 = pow2h(pkh_fma_sw0(Xp3, C_PP, pkh_mul_sw0(XA[3], C_PM)));
            acc += binpass(a0, a1, a2, a3, tbl[0*64 + L]);      // symw = 1
            acc += binpass(b0, b1, b2, b3, tbl[128*64 + L]);    // symw = 1
        } else {
            const int4 tbA = tbl[kxA*64 + L];
            acc = fmaf(2.f, binpass(pow2h(XA[0]), pow2h(XA[1]),
                                    pow2h(XA[2]), pow2h(XA[3]), tbA), acc);
        }
        acc = fmaf(2.f, binpass(pow2h(XB[0]), pow2h(XB[1]),
                                pow2h(XB[2]), pow2h(XB[3]), tbB), acc);
    }
    __syncthreads();

    // ---------------- reduce 16 waves, per-image loss ----------------
    float* bins = (float*)tile;        // tile dead now
    bins[w*64 + L] = acc;
    __syncthreads();
    if (tid < 64) {
        float tot = 0.f;
        #pragma unroll
        for (int ww = 0; ww < 16; ++ww) tot += bins[ww*64 + tid];
        const int c = cnt[tid + 1];
        const float inv = (c > 0) ? 1.0f / (float)c : 0.0f;
        const float v = tot * cscale * inv;
        const float d = logf(v + 1e-12f) - logf(mean_cl[tid] + 1e-12f);
        float l = weighting[tid] * d * d;
        #pragma unroll
        for (int o = 32; o; o >>= 1) l += __shfl_down(l, o);
        if (tid == 0) atomicAdd(out, l * invB64);
    }
}

// Prep: one block per kx row (0..255). All rows: per-segment counts. Rows
// 0..128 additionally emit the boundary table (<=2 contiguous ky-runs as
// prefix-lookup indices; 256 = zero sentinel slot).
__global__ __launch_bounds__(256) void k_prep(const int* __restrict__ seg,
                                              int4* __restrict__ tbl,
                                              int* __restrict__ cnt) {
    __shared__ int lo1[NSEG], hi1[NSEG], lo2[NSEG], hi2[NSEG], lc[NSEG];
    const int kx = blockIdx.x, ky = threadIdx.x;
    if (ky < NSEG) { lo1[ky] = 300; hi1[ky] = -1; lo2[ky] = 300; hi2[ky] = -1; lc[ky] = 0; }
    __syncthreads();
    const int s = seg[kx * 256 + ky];
    atomicAdd(&lc[s], 1);
    if (kx <= 128) {
        if (ky <= 128) { atomicMin(&lo1[s], ky); atomicMax(&hi1[s], ky); }
        else           { atomicMin(&lo2[s], ky); atomicMax(&hi2[s], ky); }
    }
    __syncthreads();
    if (ky < NSEG && lc[ky] > 0) atomicAdd(&cnt[ky], lc[ky]);
    if (kx <= 128 && ky >= 1 && ky <= 64) {
        int4 t;
        if (hi1[ky] < 0) { t.x = 256; t.y = 256; }
        else             { t.x = (lo1[ky] > 0) ? lo1[ky] - 1 : 256; t.y = hi1[ky]; }
        if (hi2[ky] < 0) { t.z = 256; t.w = 256; }
        else             { t.z = lo2[ky] - 1; t.w = hi2[ky]; }
        tbl[kx * 64 + (ky - 1)] = t;
    }
}

extern "C" void kernel_launch(void* const* d_in, const int* in_sizes, int n_in,
                              void* d_out, int out_size, void* d_ws, size_t ws_size,
                              hipStream_t stream) {
    const float* pred      = (const float*)d_in[0];
    const float* mean_cl   = (const float*)d_in[1];
    const float* weighting = (const float*)d_in[2];
    const int*   seg       = (const int*)d_in[3];
    float* out = (float*)d_out;

    const int B = in_sizes[0] / 65536;

    // ws: [cnt 66 i32, pad to 256B][boundary table 129*64 int4]
    int*  cnt = (int*)d_ws;
    int4* tbl = (int4*)((char*)d_ws + 256);

    const double rad = (5.0 * 60.0 / 256.0) * M_PI / 180.0;
    const float cscale = (float)(rad * rad / (65536.0 * 1e12)); // rad^2/N^2/TSZ^2
    const float invB64 = (float)(1.0 / ((double)B * 64.0));

    hipMemsetAsync(d_out, 0, sizeof(float), stream);
    hipMemsetAsync(cnt, 0, NSEG * sizeof(int), stream);
    k_prep<<<256, 256, 0, stream>>>(seg, tbl, cnt);
    k_fused<<<B, 1024, 0, stream>>>(pred, tbl, cnt, mean_cl, weighting,
                                    out, cscale, invB64);
}